// Round 3
// baseline (150.408 us; speedup 1.0000x reference)
//
#include <hip/hip_runtime.h>

#define POOL    7
#define RSTRIDE 16.0f
#define IMG_H   128
#define IMG_W   128
#define IMG_C   512
#define C4      (IMG_C / 4)   // float4s per pixel

// Native clang vector type: __builtin_nontemporal_store requires it
// (HIP_vector_type float4 is a class and is rejected). Same 16B layout.
typedef float f4 __attribute__((ext_vector_type(4)));

// One block (128 threads) per output ROW (n, py): 7 px * 512 ch.
// blockIdx swizzled so all rows of one RoI land on ONE XCD (dispatch is
// round-robin blockIdx%8 -> XCD). 28 independent loads per thread give the
// wave deep MLP for latency hiding.
//
// v2 changes vs 150us baseline:
//  - zero-weight tap redirect: when lx==0 (resp. ly==0) the x1 (y1) taps have
//    weight 0; point them at the x0 (y0) pixel so the "wasted" loads become
//    L1 hits on the line just fetched instead of distinct L2/L3 traffic.
//    Conditions are wave-uniform -> branchless cndmask, no divergence.
//  - nontemporal output stores: 100 MB streaming write has zero reuse; keep
//    it from evicting tap lines out of the 4 MB per-XCD L2.
template <bool SWIZZLE>
__global__ __launch_bounds__(128)
void RoiPoolingLayer_22462678958491_kernel(const float* __restrict__ image,
                                           const float* __restrict__ roi,
                                           float* __restrict__ out, int N)
{
    int n, py;
    if (SWIZZLE) {
        // grid = N*7, N%8==0: XCD x = b&7 handles RoIs [x*N/8, (x+1)*N/8)
        const int per   = N >> 3;
        const int xcd   = blockIdx.x & 7;
        const int local = blockIdx.x >> 3;        // 0 .. N*7/8-1
        const int q     = local / POOL;
        n  = xcd * per + q;
        py = local - q * POOL;
    } else {
        n  = blockIdx.x / POOL;
        py = blockIdx.x - n * POOL;
    }

    // RoI scalar math (uniform per block -> SGPRs)
    const float x = roi[n * 4 + 0];
    const float y = roi[n * 4 + 1];
    const float w = roi[n * 4 + 2];
    const float h = roi[n * 4 + 3];

    const float r  = rintf((x - 0.5f * w) / RSTRIDE);   // col start
    const float c  = rintf((y - 0.5f * h) / RSTRIDE);   // row start
    const float wq = fmaxf(rintf(w / RSTRIDE), 1.0f);
    const float hq = fmaxf(rintf(h / RSTRIDE), 1.0f);

    // y axis for this output row
    float sy = (((float)py + 0.5f) / (float)POOL) * hq - 0.5f;
    sy = fminf(fmaxf(sy, 0.0f), hq - 1.0f);
    const float fy0 = floorf(sy);
    const float ly  = sy - fy0;
    const float fy1 = fminf(fy0 + 1.0f, hq - 1.0f);
    const int iy0 = (int)fminf(fmaxf(c + fy0, 0.0f), (float)(IMG_H - 1));
    int       iy1 = (int)fminf(fmaxf(c + fy1, 0.0f), (float)(IMG_H - 1));
    if (ly == 0.0f) iy1 = iy0;        // weight-0 row: make its loads L1 hits

    const int t = threadIdx.x;                    // channel group 0..127
    const f4* row0 = (const f4*)(image + (size_t)iy0 * IMG_W * IMG_C) + t;
    const f4* row1 = (const f4*)(image + (size_t)iy1 * IMG_W * IMG_C) + t;
    f4* po = (f4*)(out + ((size_t)n * (POOL * POOL) + (size_t)py * POOL) * IMG_C) + t;

#pragma unroll
    for (int px = 0; px < POOL; ++px) {
        float sx = (((float)px + 0.5f) / (float)POOL) * wq - 0.5f;
        sx = fminf(fmaxf(sx, 0.0f), wq - 1.0f);
        const float fx0 = floorf(sx);
        const float lx  = sx - fx0;
        const float fx1 = fminf(fx0 + 1.0f, wq - 1.0f);
        const int ix0 = (int)fminf(fmaxf(r + fx0, 0.0f), (float)(IMG_W - 1));
        int       ix1 = (int)fminf(fmaxf(r + fx1, 0.0f), (float)(IMG_W - 1));
        if (lx == 0.0f) ix1 = ix0;    // weight-0 col: duplicate load -> L1 hit

        const float w00 = (1.0f - ly) * (1.0f - lx);
        const float w01 = (1.0f - ly) * lx;
        const float w10 = ly * (1.0f - lx);
        const float w11 = ly * lx;

        const f4 a  = row0[ix0 * C4];
        const f4 bb = row0[ix1 * C4];
        const f4 cc = row1[ix0 * C4];
        const f4 dd = row1[ix1 * C4];

        f4 o;
        o.x = w00 * a.x + w01 * bb.x + w10 * cc.x + w11 * dd.x;
        o.y = w00 * a.y + w01 * bb.y + w10 * cc.y + w11 * dd.y;
        o.z = w00 * a.z + w01 * bb.z + w10 * cc.z + w11 * dd.z;
        o.w = w00 * a.w + w01 * bb.w + w10 * cc.w + w11 * dd.w;
        __builtin_nontemporal_store(o, &po[px * C4]);
    }
}

extern "C" void kernel_launch(void* const* d_in, const int* in_sizes, int n_in,
                              void* d_out, int out_size, void* d_ws, size_t ws_size,
                              hipStream_t stream)
{
    const float* image = (const float*)d_in[0];   // (1,128,128,512) fp32
    const float* roi   = (const float*)d_in[1];   // (N,4) fp32
    float*       out   = (float*)d_out;           // (1,N,7,7,512) fp32

    const int N = in_sizes[1] / 4;                // 1000
    const int blocks = N * POOL;                  // 7000 row-blocks

    if ((N & 7) == 0) {
        RoiPoolingLayer_22462678958491_kernel<true><<<blocks, 128, 0, stream>>>(image, roi, out, N);
    } else {
        RoiPoolingLayer_22462678958491_kernel<false><<<blocks, 128, 0, stream>>>(image, roi, out, N);
    }
}